// Round 1
// baseline (842.299 us; speedup 1.0000x reference)
//
#include <hip/hip_runtime.h>

// WordGraphNet: 2-layer weighted graph conv, fp32.
//   h1 = leaky_relu(segmean(Wh1[src]*w -> dst)),  Wh1 = x@W1+b1
//   out = segmean(Wh2[src]*w -> dst),             Wh2 = h1@W2+b2
// Round 1: atomic-scatter baseline. Dominant cost expected: 2x76.8M atomicAdd.

#define N_NODES 50000
#define N_EDGES 1200000
#define IN_SIZE 128
#define HID 64
#define NEG_SLOPE 0.01f

// ---------------- GEMM: out[row,col] = sum_k h[row,k]*W[k,col] + b[col] ----
// One thread per output element. Wave = one row (lane = col): x reads are
// wave-uniform broadcasts, W reads are coalesced 256B rows, W tiny (L1-hot).
template <int K>
__global__ void gemm_bias_kernel(const float* __restrict__ h,
                                 const float* __restrict__ W,
                                 const float* __restrict__ b,
                                 float* __restrict__ out) {
    int gid = blockIdx.x * blockDim.x + threadIdx.x;
    if (gid >= N_NODES * HID) return;
    int row = gid >> 6;
    int col = gid & 63;
    const float* hr = h + row * K;
    float acc = b[col];
#pragma unroll 8
    for (int k = 0; k < K; ++k)
        acc = fmaf(hr[k], W[k * HID + col], acc);
    out[gid] = acc;
}

// ---------------- degree: deg[d] = # incoming edges --------------------------
__global__ void degree_kernel(const int* __restrict__ dst,
                              float* __restrict__ deg) {
    int e = blockIdx.x * blockDim.x + threadIdx.x;
    if (e < N_EDGES) atomicAdd(&deg[dst[e]], 1.0f);
}

// ---------------- scatter: acc[dst,f] += Wh[src,f] * w -----------------------
// One wave per edge, lane = feature. Gather is one coalesced 256B read from a
// 12.8MB (L2/L3-resident) table; atomics hit 64 consecutive addresses.
__global__ void scatter_kernel(const float* __restrict__ Wh,
                               const float* __restrict__ ew,
                               const int* __restrict__ src,
                               const int* __restrict__ dst,
                               float* __restrict__ acc) {
    int e = blockIdx.x * 4 + (threadIdx.x >> 6);
    if (e >= N_EDGES) return;
    int f = threadIdx.x & 63;
    int s = src[e];
    int d = dst[e];
    float w = ew[e];
    atomicAdd(&acc[d * HID + f], Wh[s * HID + f] * w);
}

// ---------------- normalize (+optional leaky relu) ---------------------------
__global__ void norm_lrelu_kernel(const float* __restrict__ acc,
                                  const float* __restrict__ deg,
                                  float* __restrict__ out) {
    int gid = blockIdx.x * blockDim.x + threadIdx.x;
    if (gid >= N_NODES * HID) return;
    int row = gid >> 6;
    float v = acc[gid] / fmaxf(deg[row], 1.0f);
    out[gid] = v >= 0.0f ? v : NEG_SLOPE * v;
}

__global__ void norm_kernel(const float* __restrict__ acc,
                            const float* __restrict__ deg,
                            float* __restrict__ out) {
    int gid = blockIdx.x * blockDim.x + threadIdx.x;
    if (gid >= N_NODES * HID) return;
    int row = gid >> 6;
    out[gid] = acc[gid] / fmaxf(deg[row], 1.0f);
}

extern "C" void kernel_launch(void* const* d_in, const int* in_sizes, int n_in,
                              void* d_out, int out_size, void* d_ws, size_t ws_size,
                              hipStream_t stream) {
    const float* x  = (const float*)d_in[0];   // [50000,128]
    const float* ew = (const float*)d_in[1];   // [1200000]
    const float* W1 = (const float*)d_in[2];   // [128,64]
    const float* b1 = (const float*)d_in[3];   // [64]
    const float* W2 = (const float*)d_in[4];   // [64,64]
    const float* b2 = (const float*)d_in[5];   // [64]
    const int* src  = (const int*)d_in[6];     // [1200000]
    const int* dst  = (const int*)d_in[7];     // [1200000]
    float* out = (float*)d_out;                // [50000,64]

    // Workspace layout (floats): bufA | acc | bufC | deg  -> 38.6 MB total
    float* bufA = (float*)d_ws;                // Wh1, then reused as h1
    float* acc  = bufA + (size_t)N_NODES * HID;
    float* bufC = acc  + (size_t)N_NODES * HID;
    float* deg  = bufC + (size_t)N_NODES * HID;

    const int NH = N_NODES * HID;              // 3,200,000
    const int nodeBlocks = (NH + 255) / 256;   // 12500
    const int edgeBlocks = (N_EDGES + 255) / 256;
    const int scatBlocks = (N_EDGES + 3) / 4;  // 4 edges (waves) per block

    // ws is poisoned to 0xAA before every call: zero acc + deg ourselves.
    hipMemsetAsync(acc, 0, (size_t)NH * sizeof(float), stream);
    hipMemsetAsync(deg, 0, (size_t)N_NODES * sizeof(float), stream);

    // Layer 1
    gemm_bias_kernel<IN_SIZE><<<nodeBlocks, 256, 0, stream>>>(x, W1, b1, bufA);
    degree_kernel<<<edgeBlocks, 256, 0, stream>>>(dst, deg);
    scatter_kernel<<<scatBlocks, 256, 0, stream>>>(bufA, ew, src, dst, acc);
    norm_lrelu_kernel<<<nodeBlocks, 256, 0, stream>>>(acc, deg, bufA); // bufA := h1

    // Layer 2
    gemm_bias_kernel<HID><<<nodeBlocks, 256, 0, stream>>>(bufA, W2, b2, bufC);
    hipMemsetAsync(acc, 0, (size_t)NH * sizeof(float), stream);
    scatter_kernel<<<scatBlocks, 256, 0, stream>>>(bufC, ew, src, dst, acc);
    norm_kernel<<<nodeBlocks, 256, 0, stream>>>(acc, deg, out);
}

// Round 2
// 562.887 us; speedup vs baseline: 1.4964x; 1.4964x over previous
//
#include <hip/hip_runtime.h>

// WordGraphNet fp32. Round 2: replace atomic scatter (2x76.8M atomics, 307MB
// HBM write each) with per-call dst-CSR build (counting sort, ~2.4M atomics)
// + gather-mean aggregation (one wave per node, lane=feature, single write).

#define N_NODES 50000
#define N_EDGES 1200000
#define IN_SIZE 128
#define HID 64
#define NEG_SLOPE 0.01f

// ---------------- GEMM: out[row,col] = sum_k h[row,k]*W[k,col] + b[col] ----
template <int K>
__global__ void gemm_bias_kernel(const float* __restrict__ h,
                                 const float* __restrict__ W,
                                 const float* __restrict__ b,
                                 float* __restrict__ out) {
    int gid = blockIdx.x * blockDim.x + threadIdx.x;
    if (gid >= N_NODES * HID) return;
    int row = gid >> 6;
    int col = gid & 63;
    const float* hr = h + row * K;
    float acc = b[col];
#pragma unroll 8
    for (int k = 0; k < K; ++k)
        acc = fmaf(hr[k], W[k * HID + col], acc);
    out[gid] = acc;
}

// ---------------- degree count (int) ----------------------------------------
__global__ void degree_kernel(const int* __restrict__ dst,
                              int* __restrict__ degi) {
    int e = blockIdx.x * blockDim.x + threadIdx.x;
    if (e < N_EDGES) atomicAdd(&degi[dst[e]], 1);
}

// ---------------- single-block exclusive scan over 50000 degrees ------------
__global__ void scan_kernel(const int* __restrict__ degi,
                            int* __restrict__ off) {
    __shared__ int wsum[16];
    __shared__ int s_carry;
    const int tid = threadIdx.x;
    const int lane = tid & 63, wid = tid >> 6;
    if (tid == 0) s_carry = 0;
    __syncthreads();
    for (int base = 0; base < N_NODES; base += 1024) {
        int i = base + tid;
        int orig = (i < N_NODES) ? degi[i] : 0;
        int v = orig;
        // inclusive wave scan
        for (int o = 1; o < 64; o <<= 1) {
            int t = __shfl_up(v, o);
            if (lane >= o) v += t;
        }
        if (lane == 63) wsum[wid] = v;
        __syncthreads();
        if (wid == 0) {
            int ws = (lane < 16) ? wsum[lane] : 0;
            for (int o = 1; o < 16; o <<= 1) {
                int t = __shfl_up(ws, o);
                if (lane >= o) ws += t;
            }
            if (lane < 16) wsum[lane] = ws;
        }
        __syncthreads();
        int wbase = (wid > 0) ? wsum[wid - 1] : 0;
        int incl = v + wbase + s_carry;          // inclusive scan value
        if (i < N_NODES) off[i] = incl - orig;   // exclusive
        __syncthreads();                          // all reads of s_carry done
        if (tid == 1023) s_carry = incl;          // block total carried over
        __syncthreads();
    }
    if (tid == 0) off[N_NODES] = s_carry;         // == N_EDGES
}

// ---------------- CSR fill: counting-sort edges by dst ----------------------
__global__ void fill_kernel(const int* __restrict__ src,
                            const int* __restrict__ dst,
                            const float* __restrict__ ew,
                            const int* __restrict__ off,
                            int* __restrict__ cursor,
                            int* __restrict__ esrc,
                            float* __restrict__ ewt) {
    int e = blockIdx.x * blockDim.x + threadIdx.x;
    if (e >= N_EDGES) return;
    int d = dst[e];
    int pos = atomicAdd(&cursor[d], 1);
    int idx = off[d] + pos;
    esrc[idx] = src[e];
    ewt[idx] = ew[e];
}

// ---------------- gather-mean aggregation -----------------------------------
// One wave per dst node, lane = feature. Batch-load up to 64 edges' (src,w)
// coalesced, broadcast via shfl, gather Wh rows (12.8MB, L2/L3-hot), fma.
template <bool LRELU>
__global__ void agg_kernel(const float* __restrict__ Wh,
                           const int* __restrict__ off,
                           const int* __restrict__ esrc,
                           const float* __restrict__ ewt,
                           float* __restrict__ out) {
    int node = blockIdx.x * 4 + (threadIdx.x >> 6);
    if (node >= N_NODES) return;
    int lane = threadIdx.x & 63;
    int beg = off[node], end = off[node + 1];
    float acc = 0.0f;
    for (int base = beg; base < end; base += 64) {
        int m = min(64, end - base);
        int s = 0;
        float w = 0.0f;
        if (lane < m) {
            s = esrc[base + lane];
            w = ewt[base + lane];
        }
        for (int j = 0; j < m; ++j) {
            int sj = __shfl(s, j);
            float wj = __shfl(w, j);
            acc = fmaf(Wh[sj * HID + lane], wj, acc);
        }
    }
    float v = acc / fmaxf((float)(end - beg), 1.0f);
    if (LRELU) v = v >= 0.0f ? v : NEG_SLOPE * v;
    out[node * HID + lane] = v;
}

extern "C" void kernel_launch(void* const* d_in, const int* in_sizes, int n_in,
                              void* d_out, int out_size, void* d_ws, size_t ws_size,
                              hipStream_t stream) {
    const float* x  = (const float*)d_in[0];   // [50000,128]
    const float* ew = (const float*)d_in[1];   // [1200000]
    const float* W1 = (const float*)d_in[2];   // [128,64]
    const float* b1 = (const float*)d_in[3];   // [64]
    const float* W2 = (const float*)d_in[4];   // [64,64]
    const float* b2 = (const float*)d_in[5];   // [64]
    const int* src  = (const int*)d_in[6];     // [1200000]
    const int* dst  = (const int*)d_in[7];     // [1200000]
    float* out = (float*)d_out;                // [50000,64]

    const int NH = N_NODES * HID;              // 3,200,000

    // Workspace layout: degi|cursor (contig, one memset) | off | esrc | ewt | bufA | bufC
    int* degi   = (int*)d_ws;                         // 50000
    int* cursor = degi + N_NODES;                     // 50000
    int* off    = cursor + N_NODES;                   // 50001
    int* esrc   = off + N_NODES + 1;                  // 1.2M
    float* ewt  = (float*)(esrc + N_EDGES);           // 1.2M
    float* bufA = ewt + N_EDGES;                      // 3.2M  (Wh1 / Wh2)
    float* bufC = bufA + NH;                          // 3.2M  (h1)
    // total ~36.2 MB

    const int nodeBlocks = (NH + 255) / 256;          // 12500
    const int edgeBlocks = (N_EDGES + 255) / 256;
    const int aggBlocks  = (N_NODES + 3) / 4;         // 12500

    // ws is poisoned 0xAA each call: zero the counters (degi+cursor adjacent).
    hipMemsetAsync(degi, 0, 2u * N_NODES * sizeof(int), stream);

    // CSR build (shared by both layers)
    degree_kernel<<<edgeBlocks, 256, 0, stream>>>(dst, degi);
    scan_kernel<<<1, 1024, 0, stream>>>(degi, off);
    fill_kernel<<<edgeBlocks, 256, 0, stream>>>(src, dst, ew, off, cursor, esrc, ewt);

    // Layer 1
    gemm_bias_kernel<IN_SIZE><<<nodeBlocks, 256, 0, stream>>>(x, W1, b1, bufA);
    agg_kernel<true><<<aggBlocks, 256, 0, stream>>>(bufA, off, esrc, ewt, bufC); // bufC := h1

    // Layer 2
    gemm_bias_kernel<HID><<<nodeBlocks, 256, 0, stream>>>(bufC, W2, b2, bufA);
    agg_kernel<false><<<aggBlocks, 256, 0, stream>>>(bufA, off, esrc, ewt, out);
}

// Round 3
// 419.563 us; speedup vs baseline: 2.0076x; 1.3416x over previous
//
#include <hip/hip_runtime.h>

// WordGraphNet fp32. Round 3:
//  - GEMM v2: LDS-staged W + 4 rows/wave + scalar (wave-uniform) x loads.
//    Round-2 GEMM was latency-bound (VALUBusy 13%, 1 global W load per FMA).
//  - agg v2: unroll edge loop x4 for memory-level parallelism on the gathers.

#define N_NODES 50000
#define N_EDGES 1200000
#define IN_SIZE 128
#define HID 64
#define NEG_SLOPE 0.01f

// ---------------- GEMM v2: C[50000,64] = x[50000,K] @ W[K,64] + b ----------
// Block = 256 thr (4 waves), 16 rows/block (4 rows/wave), lane = col.
// W fully staged in LDS; ws[k*64+lane] is 2-way bank aliasing (free).
// Row index forced wave-uniform -> x loads become scalar-cache loads.
template <int K>
__global__ __launch_bounds__(256) void gemm_v2(const float* __restrict__ x,
                                               const float* __restrict__ W,
                                               const float* __restrict__ b,
                                               float* __restrict__ out) {
    __shared__ float ws[K * 64];
    const int tid = threadIdx.x;
    for (int i = tid; i < K * 16; i += 256)          // K*64 floats = K*16 float4
        ((float4*)ws)[i] = ((const float4*)W)[i];
    __syncthreads();

    const int lane = tid & 63;
    int row0 = blockIdx.x * 16 + (tid >> 6) * 4;     // uniform per wave
    row0 = __builtin_amdgcn_readfirstlane(row0);
    const float4* xp = (const float4*)(x + (size_t)row0 * K);

    const float bias = b[lane];
    float acc0 = bias, acc1 = bias, acc2 = bias, acc3 = bias;

    for (int kk = 0; kk < K / 4; ++kk) {
        float4 x0 = xp[0 * (K / 4) + kk];            // wave-uniform -> s_load
        float4 x1 = xp[1 * (K / 4) + kk];
        float4 x2 = xp[2 * (K / 4) + kk];
        float4 x3 = xp[3 * (K / 4) + kk];
        int k = kk * 4;
        float w0 = ws[(k + 0) * 64 + lane];
        float w1 = ws[(k + 1) * 64 + lane];
        float w2 = ws[(k + 2) * 64 + lane];
        float w3 = ws[(k + 3) * 64 + lane];
        acc0 = fmaf(x0.x, w0, acc0); acc0 = fmaf(x0.y, w1, acc0);
        acc0 = fmaf(x0.z, w2, acc0); acc0 = fmaf(x0.w, w3, acc0);
        acc1 = fmaf(x1.x, w0, acc1); acc1 = fmaf(x1.y, w1, acc1);
        acc1 = fmaf(x1.z, w2, acc1); acc1 = fmaf(x1.w, w3, acc1);
        acc2 = fmaf(x2.x, w0, acc2); acc2 = fmaf(x2.y, w1, acc2);
        acc2 = fmaf(x2.z, w2, acc2); acc2 = fmaf(x2.w, w3, acc2);
        acc3 = fmaf(x3.x, w0, acc3); acc3 = fmaf(x3.y, w1, acc3);
        acc3 = fmaf(x3.z, w2, acc3); acc3 = fmaf(x3.w, w3, acc3);
    }
    float* op = out + (size_t)row0 * HID + lane;
    op[0 * HID] = acc0; op[1 * HID] = acc1; op[2 * HID] = acc2; op[3 * HID] = acc3;
}

// ---------------- degree count (int) ----------------------------------------
__global__ void degree_kernel(const int* __restrict__ dst,
                              int* __restrict__ degi) {
    int e = blockIdx.x * blockDim.x + threadIdx.x;
    if (e < N_EDGES) atomicAdd(&degi[dst[e]], 1);
}

// ---------------- single-block exclusive scan over 50000 degrees ------------
__global__ void scan_kernel(const int* __restrict__ degi,
                            int* __restrict__ off) {
    __shared__ int wsum[16];
    __shared__ int s_carry;
    const int tid = threadIdx.x;
    const int lane = tid & 63, wid = tid >> 6;
    if (tid == 0) s_carry = 0;
    __syncthreads();
    for (int base = 0; base < N_NODES; base += 1024) {
        int i = base + tid;
        int orig = (i < N_NODES) ? degi[i] : 0;
        int v = orig;
        for (int o = 1; o < 64; o <<= 1) {
            int t = __shfl_up(v, o);
            if (lane >= o) v += t;
        }
        if (lane == 63) wsum[wid] = v;
        __syncthreads();
        if (wid == 0) {
            int ws = (lane < 16) ? wsum[lane] : 0;
            for (int o = 1; o < 16; o <<= 1) {
                int t = __shfl_up(ws, o);
                if (lane >= o) ws += t;
            }
            if (lane < 16) wsum[lane] = ws;
        }
        __syncthreads();
        int wbase = (wid > 0) ? wsum[wid - 1] : 0;
        int incl = v + wbase + s_carry;
        if (i < N_NODES) off[i] = incl - orig;
        __syncthreads();
        if (tid == 1023) s_carry = incl;
        __syncthreads();
    }
    if (tid == 0) off[N_NODES] = s_carry;
}

// ---------------- CSR fill: counting-sort edges by dst ----------------------
__global__ void fill_kernel(const int* __restrict__ src,
                            const int* __restrict__ dst,
                            const float* __restrict__ ew,
                            const int* __restrict__ off,
                            int* __restrict__ cursor,
                            int* __restrict__ esrc,
                            float* __restrict__ ewt) {
    int e = blockIdx.x * blockDim.x + threadIdx.x;
    if (e >= N_EDGES) return;
    int d = dst[e];
    int pos = atomicAdd(&cursor[d], 1);
    int idx = off[d] + pos;
    esrc[idx] = src[e];
    ewt[idx] = ew[e];
}

// ---------------- gather-mean aggregation (unrolled x4) ----------------------
template <bool LRELU>
__global__ void agg_kernel(const float* __restrict__ Wh,
                           const int* __restrict__ off,
                           const int* __restrict__ esrc,
                           const float* __restrict__ ewt,
                           float* __restrict__ out) {
    int node = blockIdx.x * 4 + (threadIdx.x >> 6);
    if (node >= N_NODES) return;
    int lane = threadIdx.x & 63;
    int beg = off[node], end = off[node + 1];
    float acc = 0.0f;
    for (int base = beg; base < end; base += 64) {
        int m = min(64, end - base);
        int s = 0;
        float w = 0.0f;
        if (lane < m) {
            s = esrc[base + lane];
            w = ewt[base + lane];
        }
        int j = 0;
        for (; j + 4 <= m; j += 4) {
            int s0 = __shfl(s, j + 0), s1 = __shfl(s, j + 1);
            int s2 = __shfl(s, j + 2), s3 = __shfl(s, j + 3);
            float w0 = __shfl(w, j + 0), w1 = __shfl(w, j + 1);
            float w2 = __shfl(w, j + 2), w3 = __shfl(w, j + 3);
            float v0 = Wh[s0 * HID + lane];
            float v1 = Wh[s1 * HID + lane];
            float v2 = Wh[s2 * HID + lane];
            float v3 = Wh[s3 * HID + lane];
            acc = fmaf(v0, w0, acc);
            acc = fmaf(v1, w1, acc);
            acc = fmaf(v2, w2, acc);
            acc = fmaf(v3, w3, acc);
        }
        for (; j < m; ++j) {
            int sj = __shfl(s, j);
            float wj = __shfl(w, j);
            acc = fmaf(Wh[sj * HID + lane], wj, acc);
        }
    }
    float v = acc / fmaxf((float)(end - beg), 1.0f);
    if (LRELU) v = v >= 0.0f ? v : NEG_SLOPE * v;
    out[node * HID + lane] = v;
}

extern "C" void kernel_launch(void* const* d_in, const int* in_sizes, int n_in,
                              void* d_out, int out_size, void* d_ws, size_t ws_size,
                              hipStream_t stream) {
    const float* x  = (const float*)d_in[0];
    const float* ew = (const float*)d_in[1];
    const float* W1 = (const float*)d_in[2];
    const float* b1 = (const float*)d_in[3];
    const float* W2 = (const float*)d_in[4];
    const float* b2 = (const float*)d_in[5];
    const int* src  = (const int*)d_in[6];
    const int* dst  = (const int*)d_in[7];
    float* out = (float*)d_out;

    const int NH = N_NODES * HID;

    int* degi   = (int*)d_ws;
    int* cursor = degi + N_NODES;
    int* off    = cursor + N_NODES;
    int* esrc   = off + N_NODES + 1;
    float* ewt  = (float*)(esrc + N_EDGES);
    float* bufA = ewt + N_EDGES;
    float* bufC = bufA + NH;

    const int edgeBlocks = (N_EDGES + 255) / 256;
    const int aggBlocks  = (N_NODES + 3) / 4;
    const int gemmBlocks = N_NODES / 16;              // 3125, exact

    hipMemsetAsync(degi, 0, 2u * N_NODES * sizeof(int), stream);

    // CSR build (shared by both layers)
    degree_kernel<<<edgeBlocks, 256, 0, stream>>>(dst, degi);
    scan_kernel<<<1, 1024, 0, stream>>>(degi, off);
    fill_kernel<<<edgeBlocks, 256, 0, stream>>>(src, dst, ew, off, cursor, esrc, ewt);

    // Layer 1
    gemm_v2<IN_SIZE><<<gemmBlocks, 256, 0, stream>>>(x, W1, b1, bufA);
    agg_kernel<true><<<aggBlocks, 256, 0, stream>>>(bufA, off, esrc, ewt, bufC);

    // Layer 2
    gemm_v2<HID><<<gemmBlocks, 256, 0, stream>>>(bufC, W2, b2, bufA);
    agg_kernel<false><<<aggBlocks, 256, 0, stream>>>(bufA, off, esrc, ewt, out);
}